// Round 4
// baseline (1658.326 us; speedup 1.0000x reference)
//
#include <hip/hip_runtime.h>
#include <math.h>

#define LL     441
#define CC     64
#define NWAY   5
#define NSHOT  5
#define SS     2205      // NSHOT * LL
#define NQ     75
#define NSTRIP 21        // 441 groups / 21 per strip
#define TB     128       // main kernel block size

typedef __attribute__((ext_vector_type(2))) float f32x2;

// ---- workspace layout (float offsets) ----
#define OFF_QN    0u         // [75][441][64]
#define OFF_SUPN  2116800u   // [5][2205][64]
#define OFF_PROTO 2822400u   // [5][64]
#define OFF_V     2822720u   // [64]
#define OFF_SW    2822784u   // [5][2205]
#define OFF_RELC  2833920u   // [75][5][21][441][3]
#define OFF_T2C   13252608u  // [75][5][21][441][3]
// total 23,671,233 floats ~= 94.7 MB

__device__ __forceinline__ void top3_insert(float v, float& a, float& b, float& c) {
  bool ga = v > a;
  bool gb = v > b;
  bool gc = v > c;
  float nc = gb ? b : (gc ? v : c);
  float nb = ga ? a : (gb ? v : b);
  float na = ga ? v : a;
  a = na; b = nb; c = nc;
}

// ---------------- normalize x1 -> qn[q][l][c] ----------------
__global__ __launch_bounds__(256) void norm_q_kernel(const float* __restrict__ x,
                                                     float* __restrict__ outn) {
  const int img  = blockIdx.x;   // 0..74
  const int tile = blockIdx.y;   // 0..6
  __shared__ float tbuf[64][65];
  __shared__ float part[4][64];
  __shared__ float rn[64];
  const int t  = threadIdx.x;
  const int l0 = tile * 64;
  for (int k = 0; k < 16; k++) {
    int idx = t + k * 256;
    int c = idx >> 6, j = idx & 63;
    int l = l0 + j;
    tbuf[c][j] = (l < LL) ? x[(img * CC + c) * LL + l] : 1.0f;
  }
  __syncthreads();
  {
    int j = t & 63, q4 = t >> 6;
    float s = 0.0f;
    for (int c = q4 * 16; c < q4 * 16 + 16; c++) { float v = tbuf[c][j]; s += v * v; }
    part[q4][j] = s;
  }
  __syncthreads();
  if (t < 64) rn[t] = 1.0f / sqrtf(part[0][t] + part[1][t] + part[2][t] + part[3][t]);
  __syncthreads();
  for (int k = 0; k < 16; k++) {
    int idx = t + k * 256;
    int j = idx >> 6, c = idx & 63;
    int l = l0 + j;
    if (l < LL) outn[(img * (size_t)LL + l) * CC + c] = tbuf[c][j] * rn[j];
  }
}

// ---------------- normalize x2 -> supn[w][s][c], s = shot*441 + l2 ----------------
__global__ __launch_bounds__(256) void norm_s_kernel(const float* __restrict__ x,
                                                     float* __restrict__ supn) {
  const int img  = blockIdx.x;   // 0..24
  const int tile = blockIdx.y;   // 0..6
  __shared__ float tbuf[64][65];
  __shared__ float part[4][64];
  __shared__ float rn[64];
  const int t  = threadIdx.x;
  const int l0 = tile * 64;
  const int wv = img / NSHOT, sh = img % NSHOT;
  for (int k = 0; k < 16; k++) {
    int idx = t + k * 256;
    int c = idx >> 6, j = idx & 63;
    int l = l0 + j;
    tbuf[c][j] = (l < LL) ? x[(img * CC + c) * LL + l] : 1.0f;
  }
  __syncthreads();
  {
    int j = t & 63, q4 = t >> 6;
    float s = 0.0f;
    for (int c = q4 * 16; c < q4 * 16 + 16; c++) { float v = tbuf[c][j]; s += v * v; }
    part[q4][j] = s;
  }
  __syncthreads();
  if (t < 64) rn[t] = 1.0f / sqrtf(part[0][t] + part[1][t] + part[2][t] + part[3][t]);
  __syncthreads();
  for (int k = 0; k < 16; k++) {
    int idx = t + k * 256;
    int j = idx >> 6, c = idx & 63;
    int l = l0 + j;
    if (l < LL) supn[((size_t)wv * SS + sh * LL + l) * CC + c] = tbuf[c][j] * rn[j];
  }
}

// ---------------- proto[p][c] = mean_s supn[p][s][c] ----------------
__global__ __launch_bounds__(256) void proto_kernel(const float* __restrict__ supn,
                                                    float* __restrict__ proto) {
  const int p = blockIdx.x;
  const int t = threadIdx.x;
  __shared__ float part[4][64];
  const int c = t & 63, q4 = t >> 6;
  float s = 0.0f;
  for (int sidx = q4; sidx < SS; sidx += 4) s += supn[((size_t)p * SS + sidx) * CC + c];
  part[q4][c] = s;
  __syncthreads();
  if (t < 64)
    proto[p * CC + t] = (part[0][t] + part[1][t] + part[2][t] + part[3][t]) * (1.0f / SS);
}

// ---------------- v[c] = sum_p W_support[p] * proto[p][c] ----------------
__global__ __launch_bounds__(64) void vvec_kernel(const float* __restrict__ proto,
                                                  const float* __restrict__ Wsup,
                                                  float* __restrict__ v) {
  const int c = threadIdx.x;
  float s = 0.0f;
  for (int p = 0; p < NWAY; p++) s += Wsup[p] * proto[p * CC + c];
  v[c] = s;
}

// ---------------- sw[w*SS+s] = sigmoid(v . supn[w][s] + b_support) ----------------
__global__ __launch_bounds__(256) void sw_kernel(const float* __restrict__ supn,
                                                 const float* __restrict__ v,
                                                 const float* __restrict__ bsup,
                                                 float* __restrict__ sw) {
  const int idx = blockIdx.x * 256 + threadIdx.x;
  if (idx >= NWAY * SS) return;
  const float4* row = (const float4*)(supn + (size_t)idx * CC);
  const float4* vv  = (const float4*)v;
  float s = 0.0f;
#pragma unroll
  for (int k = 0; k < 16; k++) {
    float4 a = row[k], b = vv[k];
    s += a.x * b.x + a.y * b.y + a.z * b.z + a.w * b.w;
  }
  sw[idx] = 1.0f / (1.0f + expf(-(s + bsup[0])));
}

// ---------------- main fused kernel (v4) ----------------
// Per block (q, w, strip). Staged: 24 consecutive 5-slot groups (= 120 s slots:
// 1-group left halo, 21 owned, 2 trailing; zero-filled OOB -> reproduces conv SAME
// zero padding because max over an all-zero group is 0). NOTE: the reference's
// "max over shot" is actually max over 5 CONSECUTIVE s indices (reshape [L,SHOT]
// of a shot-major axis) — our groups match that exactly.
// 128 threads = 10 row-tiles(16) x 12 slot-tiles(10 = 2 groups). K=64 in 4 LDS
// stages of 16 channels. Each thread: 16x10 f32 register-tile GEMM via f32x2
// vector ops (v_pk_fma_f32 eligible); group max + sw-weighted top3 in registers.
// LDS correctness/conflict engineering:
//   supT [c][pslot] stride 144, pslot = st*12+j: read base st*12*4B = 48B -> 16B
//        aligned b128 reads, <=2-way banks. (v3's st*10 was 8-mod-16 misaligned!)
//   qT   [c][phys] stride 196, phys = rtt*20 + (r&15): INJECTIVE (v3's skew
//        collided rows 48..79), 16B-aligned reads, bases {0,20,8,28,16,4} mod 32.
//   Ab   stride 25 (coprime 32): conflict-free conv reads.
__global__ __launch_bounds__(128, 1) void main_kernel(
    const float* __restrict__ qn, const float* __restrict__ supn,
    const float* __restrict__ sw, const float* __restrict__ ck,
    const float* __restrict__ cb, float* __restrict__ relc, float* __restrict__ t2c) {
  const int q = blockIdx.x, w = blockIdx.y, strip = blockIdx.z;
  const int t = threadIdx.x;

  __shared__ float supT[CC * 144];      // [c][pslot]  36.9 KB
  __shared__ float qT[16 * 196];        // [c_local][phys]  12.5 KB (16-ch stage)
  __shared__ float Ab[162][25];         // A rows r0-2 .. r0+159  16.2 KB
  __shared__ float t2buf[10][4][12][3]; // 5.8 KB
  __shared__ float sws_s[120];
  __shared__ float ckl9[9];
  __shared__ float cbl_s;
  // total ~70.2 KB -> 2 blocks/CU -> 4 waves/CU (1 per SIMD)

  const int s_base = 105 * strip - 5;   // first staged s (group 21*strip - 1)

  // ---- stage sup panel, transposed into padded 12-slot tiles ----
  for (int i = t; i < 1920; i += TB) {   // 120 slots x 16 float4 c-chunks
    int slot = i % 120, cc = i / 120;
    int sg = s_base + slot;
    float4 v = make_float4(0.f, 0.f, 0.f, 0.f);
    if (sg >= 0 && sg < SS) v = *(const float4*)&supn[((size_t)w * SS + sg) * CC + cc * 4];
    int pslot = (slot / 10) * 12 + (slot % 10);
    supT[(cc * 4 + 0) * 144 + pslot] = v.x;
    supT[(cc * 4 + 1) * 144 + pslot] = v.y;
    supT[(cc * 4 + 2) * 144 + pslot] = v.z;
    supT[(cc * 4 + 3) * 144 + pslot] = v.w;
  }
  for (int i = t; i < 120; i += TB) {
    int sg = s_base + i;
    sws_s[i] = (sg >= 0 && sg < SS) ? sw[w * SS + sg] : 0.0f;
  }
  if (t < 9) ckl9[t] = ck[t];
  if (t == 0) cbl_s = cb[0];
  for (int i = t; i < 2 * 25; i += TB) Ab[i / 25][i % 25] = 0.0f;
  __syncthreads();

  const int st = t % 12, rt = t / 12;   // slot-tile, row-tile
  const bool active = (t < 120);
  const int qb = rt * 20;               // qT read base (16B aligned, clean banks)
  const int sb = st * 12;               // supT read base (16B aligned)

  // t2 validity: slot (st*10+j) must be owned, i.e. in [5,110)
  float mulj[10], addj[10];
#pragma unroll
  for (int j = 0; j < 10; j++) {
    bool vj = active && ((st >= 1 && st <= 10) || (st == 0 && j >= 5));
    mulj[j] = vj ? sws_s[st * 10 + j] : 0.0f;
    addj[j] = vj ? 0.0f : -3.0e38f;
  }

  f32x2 acc2[16][5];

  for (int band = 0; band < 3; band++) {
    const int r0 = band * 160;
    const f32x2 zero2 = {0.0f, 0.0f};
#pragma unroll
    for (int i = 0; i < 16; i++)
#pragma unroll
      for (int k = 0; k < 5; k++) acc2[i][k] = zero2;

    for (int stage = 0; stage < 4; stage++) {
      // stage qT for channels [16*stage, 16*stage+16)
      for (int i = t; i < 640; i += TB) {   // 160 rows x 4 float4-chunks
        int r = i >> 2, cc = i & 3;
        int l = r0 + r;
        float4 v = make_float4(0.f, 0.f, 0.f, 0.f);
        if (l < LL) v = *(const float4*)&qn[((size_t)q * LL + l) * CC + stage * 16 + cc * 4];
        int phys = (r >> 4) * 20 + (r & 15);
        qT[(cc * 4 + 0) * 196 + phys] = v.x;
        qT[(cc * 4 + 1) * 196 + phys] = v.y;
        qT[(cc * 4 + 2) * 196 + phys] = v.z;
        qT[(cc * 4 + 3) * 196 + phys] = v.w;
      }
      __syncthreads();
      if (active) {
#pragma unroll 4
        for (int c = 0; c < 16; c++) {
          const float* qrow = &qT[c * 196 + qb];
          const float* srow = &supT[(stage * 16 + c) * 144 + sb];
          float4 q0 = *(const float4*)&qrow[0];
          float4 q1 = *(const float4*)&qrow[4];
          float4 q2 = *(const float4*)&qrow[8];
          float4 q3 = *(const float4*)&qrow[12];
          float4 s01 = *(const float4*)&srow[0];
          float4 s23 = *(const float4*)&srow[4];
          f32x2 s4 = *(const f32x2*)&srow[8];
          float qf[16] = {q0.x, q0.y, q0.z, q0.w, q1.x, q1.y, q1.z, q1.w,
                          q2.x, q2.y, q2.z, q2.w, q3.x, q3.y, q3.z, q3.w};
          f32x2 sf2[5];
          sf2[0].x = s01.x; sf2[0].y = s01.y;
          sf2[1].x = s01.z; sf2[1].y = s01.w;
          sf2[2].x = s23.x; sf2[2].y = s23.y;
          sf2[3].x = s23.z; sf2[3].y = s23.w;
          sf2[4] = s4;
#pragma unroll
          for (int i = 0; i < 16; i++) {
            f32x2 qq; qq.x = qf[i]; qq.y = qf[i];
#pragma unroll
            for (int k = 0; k < 5; k++) acc2[i][k] += qq * sf2[k];
          }
        }
      }
      __syncthreads();   // GEMM reads done before qT restage
    }

    // ---- 5-consecutive-slot group max (in registers) -> Ab ----
    if (active) {
#pragma unroll
      for (int r = 0; r < 16; r++) {
        float g0 = fmaxf(fmaxf(fmaxf(acc2[r][0].x, acc2[r][0].y),
                               fmaxf(acc2[r][1].x, acc2[r][1].y)), acc2[r][2].x);
        float g1 = fmaxf(fmaxf(fmaxf(acc2[r][2].y, acc2[r][3].x),
                               fmaxf(acc2[r][3].y, acc2[r][4].x)), acc2[r][4].y);
        int row = rt * 16 + r;
        Ab[row + 2][st * 2]     = g0;
        Ab[row + 2][st * 2 + 1] = g1;
      }
    }

    // ---- t2: per-thread top3 of sw*dot (registers), per-row merge via small LDS ----
#pragma unroll
    for (int ch = 0; ch < 4; ch++) {
      if (active) {
#pragma unroll
        for (int rr = 0; rr < 4; rr++) {
          const int r = ch * 4 + rr;
          float a = -3.0e38f, b = -3.0e38f, c3 = -3.0e38f;
#pragma unroll
          for (int k = 0; k < 5; k++) {
            float v0 = fmaf(mulj[2 * k],     acc2[r][k].x, addj[2 * k]);
            float v1 = fmaf(mulj[2 * k + 1], acc2[r][k].y, addj[2 * k + 1]);
            top3_insert(v0, a, b, c3);
            top3_insert(v1, a, b, c3);
          }
          t2buf[rt][rr][st][0] = a;
          t2buf[rt][rr][st][1] = b;
          t2buf[rt][rr][st][2] = c3;
        }
      }
      __syncthreads();
      if (t < 40) {
        int mrt = t >> 2, rr = t & 3;
        int l = r0 + mrt * 16 + ch * 4 + rr;
        if (l < LL) {
          float a = -3.0e38f, b = -3.0e38f, c3 = -3.0e38f;
#pragma unroll
          for (int s2 = 0; s2 < 12; s2++) {
            top3_insert(t2buf[mrt][rr][s2][0], a, b, c3);
            top3_insert(t2buf[mrt][rr][s2][1], a, b, c3);
            top3_insert(t2buf[mrt][rr][s2][2], a, b, c3);
          }
          float* p = &t2c[((((size_t)q * NWAY + w) * NSTRIP + strip) * LL + l) * 3];
          p[0] = a; p[1] = b; p[2] = c3;
        }
      }
      __syncthreads();
    }

    // ---- 3x3 conv (SAME) + per-row strip top3 -> relc ----
    {
      float k0 = ckl9[0], k1 = ckl9[1], k2 = ckl9[2];
      float k3 = ckl9[3], k4 = ckl9[4], k5 = ckl9[5];
      float k6 = ckl9[6], k7 = ckl9[7], k8 = ckl9[8];
      float bias = cbl_s;
      for (int i2 = t; i2 < 160; i2 += TB) {
        int cr = r0 - 1 + i2;
        if (cr >= 0 && cr < LL) {
          float rowa[23], rowb[23], rowc[23];
#pragma unroll
          for (int k = 0; k < 23; k++) {
            rowa[k] = Ab[i2][k];
            rowb[k] = Ab[i2 + 1][k];
            rowc[k] = Ab[i2 + 2][k];
          }
          float a = -3.0e38f, b = -3.0e38f, c3 = -3.0e38f;
#pragma unroll
          for (int oc = 0; oc < 21; oc++) {
            float s = bias;
            s = fmaf(k0, rowa[oc], s); s = fmaf(k1, rowa[oc + 1], s); s = fmaf(k2, rowa[oc + 2], s);
            s = fmaf(k3, rowb[oc], s); s = fmaf(k4, rowb[oc + 1], s); s = fmaf(k5, rowb[oc + 2], s);
            s = fmaf(k6, rowc[oc], s); s = fmaf(k7, rowc[oc + 1], s); s = fmaf(k8, rowc[oc + 2], s);
            top3_insert(s, a, b, c3);
          }
          float* p = &relc[((((size_t)q * NWAY + w) * NSTRIP + strip) * LL + cr) * 3];
          p[0] = a; p[1] = b; p[2] = c3;
        }
      }
    }
    __syncthreads();
    // roll last two A rows to front (carry for next band's conv halo)
    if (t < 50) {
      int r2 = t / 25, col = t % 25;
      Ab[r2][col] = Ab[160 + r2][col];
    }
    __syncthreads();
  }
}

// ---------------- final merge: relation, wq, t2, output ----------------
__global__ __launch_bounds__(512) void final_kernel(const float* __restrict__ relc,
                                                    const float* __restrict__ t2c,
                                                    const float* __restrict__ Ww,
                                                    const float* __restrict__ bw,
                                                    float* __restrict__ out) {
  const int q = blockIdx.x;
  const int l = threadIdx.x;
  float contrib[NWAY];
  if (l < LL) {
    float relsum[NWAY], t2sum[NWAY];
    for (int w = 0; w < NWAY; w++) {
      const float* pr = &relc[(((size_t)q * NWAY + w) * NSTRIP) * LL * 3 + (size_t)l * 3];
      float a = -3.0e38f, b = -3.0e38f, c = -3.0e38f;
      for (int stp = 0; stp < NSTRIP; stp++) {
        const float* pp = pr + (size_t)stp * LL * 3;
        top3_insert(pp[0], a, b, c);
        top3_insert(pp[1], a, b, c);
        top3_insert(pp[2], a, b, c);
      }
      relsum[w] = a + b + c;
      const float* pt = &t2c[(((size_t)q * NWAY + w) * NSTRIP) * LL * 3 + (size_t)l * 3];
      a = -3.0e38f; b = -3.0e38f; c = -3.0e38f;
      for (int stp = 0; stp < NSTRIP; stp++) {
        const float* pp = pt + (size_t)stp * LL * 3;
        top3_insert(pp[0], a, b, c);
        top3_insert(pp[1], a, b, c);
        top3_insert(pp[2], a, b, c);
      }
      t2sum[w] = a + b + c;
    }
    float z = bw[0];
    for (int w = 0; w < NWAY; w++) z += Ww[w] * relsum[w];
    float wq = 1.0f / (1.0f + expf(-z));
    for (int w = 0; w < NWAY; w++) contrib[w] = wq * t2sum[w];
  } else {
    for (int w = 0; w < NWAY; w++) contrib[w] = 0.0f;
  }
  __shared__ float red[512];
  for (int w = 0; w < NWAY; w++) {
    red[threadIdx.x] = contrib[w];
    __syncthreads();
    for (int s = 256; s > 0; s >>= 1) {
      if (threadIdx.x < s) red[threadIdx.x] += red[threadIdx.x + s];
      __syncthreads();
    }
    if (threadIdx.x == 0) out[q * NWAY + w] = red[0];
    __syncthreads();
  }
}

extern "C" void kernel_launch(void* const* d_in, const int* in_sizes, int n_in,
                              void* d_out, int out_size, void* d_ws, size_t ws_size,
                              hipStream_t stream) {
  (void)in_sizes; (void)n_in; (void)out_size; (void)ws_size;
  const float* x1   = (const float*)d_in[0];
  const float* x2   = (const float*)d_in[1];
  const float* Wsup = (const float*)d_in[2];
  const float* bsup = (const float*)d_in[3];
  const float* ck   = (const float*)d_in[4];
  const float* cb   = (const float*)d_in[5];
  const float* Ww   = (const float*)d_in[6];
  const float* bw   = (const float*)d_in[7];
  float* out = (float*)d_out;
  float* ws  = (float*)d_ws;

  float* qn    = ws + OFF_QN;
  float* supn  = ws + OFF_SUPN;
  float* proto = ws + OFF_PROTO;
  float* v     = ws + OFF_V;
  float* swp   = ws + OFF_SW;
  float* relc  = ws + OFF_RELC;
  float* t2c   = ws + OFF_T2C;

  hipLaunchKernelGGL(norm_q_kernel, dim3(NQ, 7), dim3(256), 0, stream, x1, qn);
  hipLaunchKernelGGL(norm_s_kernel, dim3(NWAY * NSHOT, 7), dim3(256), 0, stream, x2, supn);
  hipLaunchKernelGGL(proto_kernel, dim3(NWAY), dim3(256), 0, stream, supn, proto);
  hipLaunchKernelGGL(vvec_kernel, dim3(1), dim3(64), 0, stream, proto, Wsup, v);
  hipLaunchKernelGGL(sw_kernel, dim3((NWAY * SS + 255) / 256), dim3(256), 0, stream,
                     supn, v, bsup, swp);
  hipLaunchKernelGGL(main_kernel, dim3(NQ, NWAY, NSTRIP), dim3(TB), 0, stream,
                     qn, supn, swp, ck, cb, relc, t2c);
  hipLaunchKernelGGL(final_kernel, dim3(NQ), dim3(512), 0, stream, relc, t2c, Ww, bw, out);
}

// Round 6
// 1301.655 us; speedup vs baseline: 1.2740x; 1.2740x over previous
//
#include <hip/hip_runtime.h>
#include <math.h>

#define LL     441
#define CC     64
#define NWAY   5
#define NSHOT  5
#define SS     2205      // NSHOT * LL
#define NQ     75
#define NSTRIP 21        // 441 groups / 21 per strip
#define TB     256       // main kernel block size
#define NWG    7875      // 75*5*21

typedef __attribute__((ext_vector_type(2))) float f32x2;

// ---- workspace layout (float offsets) ----
#define OFF_QN    0u         // [75][441][64]
#define OFF_SUPN  2116800u   // [5][2205][64]
#define OFF_PROTO 2822400u   // [5][64]
#define OFF_V     2822720u   // [64]
#define OFF_SW    2822784u   // [5][2205]
#define OFF_RELC  2833920u   // [75][5][21][441][3]
#define OFF_T2C   13252608u  // [75][5][21][441][3]
// total 23,671,233 floats ~= 94.7 MB

__device__ __forceinline__ void top3_insert(float v, float& a, float& b, float& c) {
  bool ga = v > a;
  bool gb = v > b;
  bool gc = v > c;
  float nc = gb ? b : (gc ? v : c);
  float nb = ga ? a : (gb ? v : b);
  float na = ga ? v : a;
  a = na; b = nb; c = nc;
}

// ---------------- normalize x1 -> qn[q][l][c] ----------------
__global__ __launch_bounds__(256) void norm_q_kernel(const float* __restrict__ x,
                                                     float* __restrict__ outn) {
  const int img  = blockIdx.x;   // 0..74
  const int tile = blockIdx.y;   // 0..6
  __shared__ float tbuf[64][65];
  __shared__ float part[4][64];
  __shared__ float rn[64];
  const int t  = threadIdx.x;
  const int l0 = tile * 64;
  for (int k = 0; k < 16; k++) {
    int idx = t + k * 256;
    int c = idx >> 6, j = idx & 63;
    int l = l0 + j;
    tbuf[c][j] = (l < LL) ? x[(img * CC + c) * LL + l] : 1.0f;
  }
  __syncthreads();
  {
    int j = t & 63, q4 = t >> 6;
    float s = 0.0f;
    for (int c = q4 * 16; c < q4 * 16 + 16; c++) { float v = tbuf[c][j]; s += v * v; }
    part[q4][j] = s;
  }
  __syncthreads();
  if (t < 64) rn[t] = 1.0f / sqrtf(part[0][t] + part[1][t] + part[2][t] + part[3][t]);
  __syncthreads();
  for (int k = 0; k < 16; k++) {
    int idx = t + k * 256;
    int j = idx >> 6, c = idx & 63;
    int l = l0 + j;
    if (l < LL) outn[(img * (size_t)LL + l) * CC + c] = tbuf[c][j] * rn[j];
  }
}

// ---------------- normalize x2 -> supn[w][s][c], s = shot*441 + l2 ----------------
__global__ __launch_bounds__(256) void norm_s_kernel(const float* __restrict__ x,
                                                     float* __restrict__ supn) {
  const int img  = blockIdx.x;   // 0..24
  const int tile = blockIdx.y;   // 0..6
  __shared__ float tbuf[64][65];
  __shared__ float part[4][64];
  __shared__ float rn[64];
  const int t  = threadIdx.x;
  const int l0 = tile * 64;
  const int wv = img / NSHOT, sh = img % NSHOT;
  for (int k = 0; k < 16; k++) {
    int idx = t + k * 256;
    int c = idx >> 6, j = idx & 63;
    int l = l0 + j;
    tbuf[c][j] = (l < LL) ? x[(img * CC + c) * LL + l] : 1.0f;
  }
  __syncthreads();
  {
    int j = t & 63, q4 = t >> 6;
    float s = 0.0f;
    for (int c = q4 * 16; c < q4 * 16 + 16; c++) { float v = tbuf[c][j]; s += v * v; }
    part[q4][j] = s;
  }
  __syncthreads();
  if (t < 64) rn[t] = 1.0f / sqrtf(part[0][t] + part[1][t] + part[2][t] + part[3][t]);
  __syncthreads();
  for (int k = 0; k < 16; k++) {
    int idx = t + k * 256;
    int j = idx >> 6, c = idx & 63;
    int l = l0 + j;
    if (l < LL) supn[((size_t)wv * SS + sh * LL + l) * CC + c] = tbuf[c][j] * rn[j];
  }
}

// ---------------- proto[p][c] = mean_s supn[p][s][c] ----------------
__global__ __launch_bounds__(256) void proto_kernel(const float* __restrict__ supn,
                                                    float* __restrict__ proto) {
  const int p = blockIdx.x;
  const int t = threadIdx.x;
  __shared__ float part[4][64];
  const int c = t & 63, q4 = t >> 6;
  float s = 0.0f;
  for (int sidx = q4; sidx < SS; sidx += 4) s += supn[((size_t)p * SS + sidx) * CC + c];
  part[q4][c] = s;
  __syncthreads();
  if (t < 64)
    proto[p * CC + t] = (part[0][t] + part[1][t] + part[2][t] + part[3][t]) * (1.0f / SS);
}

// ---------------- v[c] = sum_p W_support[p] * proto[p][c] ----------------
__global__ __launch_bounds__(64) void vvec_kernel(const float* __restrict__ proto,
                                                  const float* __restrict__ Wsup,
                                                  float* __restrict__ v) {
  const int c = threadIdx.x;
  float s = 0.0f;
  for (int p = 0; p < NWAY; p++) s += Wsup[p] * proto[p * CC + c];
  v[c] = s;
}

// ---------------- sw[w*SS+s] = sigmoid(v . supn[w][s] + b_support) ----------------
__global__ __launch_bounds__(256) void sw_kernel(const float* __restrict__ supn,
                                                 const float* __restrict__ v,
                                                 const float* __restrict__ bsup,
                                                 float* __restrict__ sw) {
  const int idx = blockIdx.x * 256 + threadIdx.x;
  if (idx >= NWAY * SS) return;
  const float4* row = (const float4*)(supn + (size_t)idx * CC);
  const float4* vv  = (const float4*)v;
  float s = 0.0f;
#pragma unroll
  for (int k = 0; k < 16; k++) {
    float4 a = row[k], b = vv[k];
    s += a.x * b.x + a.y * b.y + a.z * b.z + a.w * b.w;
  }
  sw[idx] = 1.0f / (1.0f + expf(-(s + bsup[0])));
}

// ---------------- main fused kernel (v5, re-audited resubmission) ----------------
// Rocprof (v4): VALUBusy 46%, Occ 11.5%, VGPR 148 < 160-reg accumulator -> spills;
// FETCH 447 MB (poor L2 locality). Fixes:
//  * 256 threads, per-thread tile 8 rows x 10 slots (acc = 80 VGPR, fits).
//    20 row-tiles(8) x 12 slot-tiles(10). 8 waves/CU = 2/SIMD (2 blocks/CU).
//  * 1D grid with bijective XCD chunk swizzle (q-major) for L2 locality.
//  * supT unpadded (b64 reads, bank-verified conflict-free); qT stride 244.
// LDS: supT 30.7K + qT 15.6K + Ab 16.2K + t2buf 5.8K + misc ~0.6K = 68.8 KB.
__global__ __launch_bounds__(256, 2) void main_kernel(
    const float* __restrict__ qn, const float* __restrict__ supn,
    const float* __restrict__ sw, const float* __restrict__ ck,
    const float* __restrict__ cb, float* __restrict__ relc, float* __restrict__ t2c) {
  const int t = threadIdx.x;

  // bijective XCD chunk swizzle: each XCD gets a contiguous q-major oid range
  const int bid = blockIdx.x;
  const int xcd = bid & 7, pos = bid >> 3;
  const int qd = NWG / 8;            // 984
  const int rm = NWG - qd * 8;       // 3
  const int base = (xcd < rm) ? xcd * (qd + 1) : rm * (qd + 1) + (xcd - rm) * qd;
  const int oid = base + pos;
  const int q = oid / 105;
  const int rem2 = oid - q * 105;
  const int w = rem2 / 21;
  const int strip = rem2 - w * 21;

  __shared__ float supT[CC * 120];      // [c][slot]        30.7 KB
  __shared__ float qT[16 * 244];        // [c_local][phys]  15.6 KB
  __shared__ float Ab[162][25];         // rows r0-2..r0+159 16.2 KB
  __shared__ float t2buf[20][2][12][3]; // 5.8 KB
  __shared__ float sws_s[120];
  __shared__ float ckl9[9];
  __shared__ float cbl_s;

  const int s_base = 105 * strip - 5;   // first staged s (group 21*strip - 1)

  // ---- stage sup panel, transposed [c][slot] ----
  for (int i = t; i < 1920; i += TB) {   // 120 slots x 16 float4 c-chunks
    int slot = i % 120, cc = i / 120;
    int sg = s_base + slot;
    float4 v = make_float4(0.f, 0.f, 0.f, 0.f);
    if (sg >= 0 && sg < SS) v = *(const float4*)&supn[((size_t)w * SS + sg) * CC + cc * 4];
    supT[(cc * 4 + 0) * 120 + slot] = v.x;
    supT[(cc * 4 + 1) * 120 + slot] = v.y;
    supT[(cc * 4 + 2) * 120 + slot] = v.z;
    supT[(cc * 4 + 3) * 120 + slot] = v.w;
  }
  for (int i = t; i < 120; i += TB) {
    int sg = s_base + i;
    sws_s[i] = (sg >= 0 && sg < SS) ? sw[w * SS + sg] : 0.0f;
  }
  if (t < 9) ckl9[t] = ck[t];
  if (t == 0) cbl_s = cb[0];
  for (int i = t; i < 2 * 25; i += TB) Ab[i / 25][i % 25] = 0.0f;
  __syncthreads();

  const int st = t % 12, rt = t / 12;   // slot-tile (0..11), row-tile (0..19 active)
  const bool active = (t < 240);
  const int qb = rt * 12;               // qT read base (16B aligned; wave-banks disjoint)
  const int sb = st * 10;               // supT read base (8B aligned; banks distinct)

  // t2 validity: slot (st*10+j) must be owned, i.e. in [5,110)
  float mulj[10], addj[10];
#pragma unroll
  for (int j = 0; j < 10; j++) {
    bool vj = active && ((st >= 1 && st <= 10) || (st == 0 && j >= 5));
    mulj[j] = vj ? sws_s[st * 10 + j] : 0.0f;
    addj[j] = vj ? 0.0f : -3.0e38f;
  }

  f32x2 acc2[8][5];

  for (int band = 0; band < 3; band++) {
    const int r0 = band * 160;
    const f32x2 zero2 = {0.0f, 0.0f};
#pragma unroll
    for (int i = 0; i < 8; i++)
#pragma unroll
      for (int k = 0; k < 5; k++) acc2[i][k] = zero2;

    for (int stage = 0; stage < 4; stage++) {
      // stage qT for channels [16*stage, 16*stage+16)
      for (int i = t; i < 640; i += TB) {   // 160 rows x 4 float4-chunks
        int rr = i >> 2, cc = i & 3;
        int l = r0 + rr;
        float4 v = make_float4(0.f, 0.f, 0.f, 0.f);
        if (l < LL) v = *(const float4*)&qn[((size_t)q * LL + l) * CC + stage * 16 + cc * 4];
        int phys = (rr >> 3) * 12 + (rr & 7);
        qT[(cc * 4 + 0) * 244 + phys] = v.x;
        qT[(cc * 4 + 1) * 244 + phys] = v.y;
        qT[(cc * 4 + 2) * 244 + phys] = v.z;
        qT[(cc * 4 + 3) * 244 + phys] = v.w;
      }
      __syncthreads();
      if (active) {
#pragma unroll 4
        for (int c = 0; c < 16; c++) {
          const float* qrow = &qT[c * 244 + qb];
          const float* srow = &supT[(stage * 16 + c) * 120 + sb];
          float4 qa = *(const float4*)&qrow[0];
          float4 qbv = *(const float4*)&qrow[4];
          f32x2 sf0 = *(const f32x2*)&srow[0];
          f32x2 sf1 = *(const f32x2*)&srow[2];
          f32x2 sf2v = *(const f32x2*)&srow[4];
          f32x2 sf3 = *(const f32x2*)&srow[6];
          f32x2 sf4 = *(const f32x2*)&srow[8];
          float qf[8] = {qa.x, qa.y, qa.z, qa.w, qbv.x, qbv.y, qbv.z, qbv.w};
#pragma unroll
          for (int i = 0; i < 8; i++) {
            f32x2 qq; qq.x = qf[i]; qq.y = qf[i];
            acc2[i][0] += qq * sf0;
            acc2[i][1] += qq * sf1;
            acc2[i][2] += qq * sf2v;
            acc2[i][3] += qq * sf3;
            acc2[i][4] += qq * sf4;
          }
        }
      }
      __syncthreads();   // GEMM reads done before qT restage
    }

    // ---- 5-consecutive-slot group max (in registers) -> Ab ----
    if (active) {
#pragma unroll
      for (int r = 0; r < 8; r++) {
        float g0 = fmaxf(fmaxf(fmaxf(acc2[r][0].x, acc2[r][0].y),
                               fmaxf(acc2[r][1].x, acc2[r][1].y)), acc2[r][2].x);
        float g1 = fmaxf(fmaxf(fmaxf(acc2[r][2].y, acc2[r][3].x),
                               fmaxf(acc2[r][3].y, acc2[r][4].x)), acc2[r][4].y);
        int row = rt * 8 + r;
        Ab[row + 2][st * 2]     = g0;
        Ab[row + 2][st * 2 + 1] = g1;
      }
    }

    // ---- t2: per-thread top3 of sw*dot (registers), per-row merge via small LDS ----
#pragma unroll
    for (int ch = 0; ch < 4; ch++) {
      if (active) {
#pragma unroll
        for (int rr2 = 0; rr2 < 2; rr2++) {
          const int r = ch * 2 + rr2;
          float a = -3.0e38f, b = -3.0e38f, c3 = -3.0e38f;
#pragma unroll
          for (int k = 0; k < 5; k++) {
            float v0 = fmaf(mulj[2 * k],     acc2[r][k].x, addj[2 * k]);
            float v1 = fmaf(mulj[2 * k + 1], acc2[r][k].y, addj[2 * k + 1]);
            top3_insert(v0, a, b, c3);
            top3_insert(v1, a, b, c3);
          }
          t2buf[rt][rr2][st][0] = a;
          t2buf[rt][rr2][st][1] = b;
          t2buf[rt][rr2][st][2] = c3;
        }
      }
      __syncthreads();
      if (t < 40) {
        int mrt = t >> 1, rr2 = t & 1;
        int l = r0 + mrt * 8 + ch * 2 + rr2;
        if (l < LL) {
          float a = -3.0e38f, b = -3.0e38f, c3 = -3.0e38f;
#pragma unroll
          for (int s2 = 0; s2 < 12; s2++) {
            top3_insert(t2buf[mrt][rr2][s2][0], a, b, c3);
            top3_insert(t2buf[mrt][rr2][s2][1], a, b, c3);
            top3_insert(t2buf[mrt][rr2][s2][2], a, b, c3);
          }
          float* p = &t2c[((((size_t)q * NWAY + w) * NSTRIP + strip) * LL + l) * 3];
          p[0] = a; p[1] = b; p[2] = c3;
        }
      }
      __syncthreads();
    }

    // ---- 3x3 conv (SAME) + per-row strip top3 -> relc ----
    if (t < 160) {
      float k0 = ckl9[0], k1 = ckl9[1], k2 = ckl9[2];
      float k3 = ckl9[3], k4 = ckl9[4], k5 = ckl9[5];
      float k6 = ckl9[6], k7 = ckl9[7], k8 = ckl9[8];
      float bias = cbl_s;
      int i2 = t;
      int cr = r0 - 1 + i2;
      if (cr >= 0 && cr < LL) {
        float rowa[23], rowb[23], rowc[23];
#pragma unroll
        for (int k = 0; k < 23; k++) {
          rowa[k] = Ab[i2][k];
          rowb[k] = Ab[i2 + 1][k];
          rowc[k] = Ab[i2 + 2][k];
        }
        float a = -3.0e38f, b = -3.0e38f, c3 = -3.0e38f;
#pragma unroll
        for (int oc = 0; oc < 21; oc++) {
          float s = bias;
          s = fmaf(k0, rowa[oc], s); s = fmaf(k1, rowa[oc + 1], s); s = fmaf(k2, rowa[oc + 2], s);
          s = fmaf(k3, rowb[oc], s); s = fmaf(k4, rowb[oc + 1], s); s = fmaf(k5, rowb[oc + 2], s);
          s = fmaf(k6, rowc[oc], s); s = fmaf(k7, rowc[oc + 1], s); s = fmaf(k8, rowc[oc + 2], s);
          top3_insert(s, a, b, c3);
        }
        float* p = &relc[((((size_t)q * NWAY + w) * NSTRIP + strip) * LL + cr) * 3];
        p[0] = a; p[1] = b; p[2] = c3;
      }
    }
    __syncthreads();
    // roll last two A rows to front (carry for next band's conv halo)
    if (t < 50) {
      int r2 = t / 25, col = t % 25;
      Ab[r2][col] = Ab[160 + r2][col];
    }
    __syncthreads();
  }
}

// ---------------- final merge: relation, wq, t2, output ----------------
__global__ __launch_bounds__(512) void final_kernel(const float* __restrict__ relc,
                                                    const float* __restrict__ t2c,
                                                    const float* __restrict__ Ww,
                                                    const float* __restrict__ bw,
                                                    float* __restrict__ out) {
  const int q = blockIdx.x;
  const int l = threadIdx.x;
  float contrib[NWAY];
  if (l < LL) {
    float relsum[NWAY], t2sum[NWAY];
    for (int w = 0; w < NWAY; w++) {
      const float* pr = &relc[(((size_t)q * NWAY + w) * NSTRIP) * LL * 3 + (size_t)l * 3];
      float a = -3.0e38f, b = -3.0e38f, c = -3.0e38f;
      for (int stp = 0; stp < NSTRIP; stp++) {
        const float* pp = pr + (size_t)stp * LL * 3;
        top3_insert(pp[0], a, b, c);
        top3_insert(pp[1], a, b, c);
        top3_insert(pp[2], a, b, c);
      }
      relsum[w] = a + b + c;
      const float* pt = &t2c[(((size_t)q * NWAY + w) * NSTRIP) * LL * 3 + (size_t)l * 3];
      a = -3.0e38f; b = -3.0e38f; c = -3.0e38f;
      for (int stp = 0; stp < NSTRIP; stp++) {
        const float* pp = pt + (size_t)stp * LL * 3;
        top3_insert(pp[0], a, b, c);
        top3_insert(pp[1], a, b, c);
        top3_insert(pp[2], a, b, c);
      }
      t2sum[w] = a + b + c;
    }
    float z = bw[0];
    for (int w = 0; w < NWAY; w++) z += Ww[w] * relsum[w];
    float wq = 1.0f / (1.0f + expf(-z));
    for (int w = 0; w < NWAY; w++) contrib[w] = wq * t2sum[w];
  } else {
    for (int w = 0; w < NWAY; w++) contrib[w] = 0.0f;
  }
  __shared__ float red[512];
  for (int w = 0; w < NWAY; w++) {
    red[threadIdx.x] = contrib[w];
    __syncthreads();
    for (int s = 256; s > 0; s >>= 1) {
      if (threadIdx.x < s) red[threadIdx.x] += red[threadIdx.x + s];
      __syncthreads();
    }
    if (threadIdx.x == 0) out[q * NWAY + w] = red[0];
    __syncthreads();
  }
}

extern "C" void kernel_launch(void* const* d_in, const int* in_sizes, int n_in,
                              void* d_out, int out_size, void* d_ws, size_t ws_size,
                              hipStream_t stream) {
  (void)in_sizes; (void)n_in; (void)out_size; (void)ws_size;
  const float* x1   = (const float*)d_in[0];
  const float* x2   = (const float*)d_in[1];
  const float* Wsup = (const float*)d_in[2];
  const float* bsup = (const float*)d_in[3];
  const float* ck   = (const float*)d_in[4];
  const float* cb   = (const float*)d_in[5];
  const float* Ww   = (const float*)d_in[6];
  const float* bw   = (const float*)d_in[7];
  float* out = (float*)d_out;
  float* ws  = (float*)d_ws;

  float* qn    = ws + OFF_QN;
  float* supn  = ws + OFF_SUPN;
  float* proto = ws + OFF_PROTO;
  float* v     = ws + OFF_V;
  float* swp   = ws + OFF_SW;
  float* relc  = ws + OFF_RELC;
  float* t2c   = ws + OFF_T2C;

  hipLaunchKernelGGL(norm_q_kernel, dim3(NQ, 7), dim3(256), 0, stream, x1, qn);
  hipLaunchKernelGGL(norm_s_kernel, dim3(NWAY * NSHOT, 7), dim3(256), 0, stream, x2, supn);
  hipLaunchKernelGGL(proto_kernel, dim3(NWAY), dim3(256), 0, stream, supn, proto);
  hipLaunchKernelGGL(vvec_kernel, dim3(1), dim3(64), 0, stream, proto, Wsup, v);
  hipLaunchKernelGGL(sw_kernel, dim3((NWAY * SS + 255) / 256), dim3(256), 0, stream,
                     supn, v, bsup, swp);
  hipLaunchKernelGGL(main_kernel, dim3(NWG), dim3(TB), 0, stream,
                     qn, supn, swp, ck, cb, relc, t2c);
  hipLaunchKernelGGL(final_kernel, dim3(NQ), dim3(512), 0, stream, relc, t2c, Ww, bw, out);
}

// Round 9
// 972.726 us; speedup vs baseline: 1.7048x; 1.3382x over previous
//
#include <hip/hip_runtime.h>
#include <math.h>

#define LL     441
#define CC     64
#define NWAY   5
#define NSHOT  5
#define SS     2205      // NSHOT * LL
#define NQ     75
#define NSTRIP 21        // 441 groups / 21 per strip
#define TB     256       // main kernel block size
#define NWG    7875      // 75*5*21

typedef __attribute__((ext_vector_type(8))) short bf16x8;
typedef __attribute__((ext_vector_type(4))) float f32x4;

// ---- workspace layout (float offsets) ----
#define OFF_QN    0u         // [75][441][64] f32
#define OFF_SUPN  2116800u   // [5][2205][64] f32
#define OFF_PROTO 2822400u   // [5][64]
#define OFF_V     2822720u   // [64]
#define OFF_SW    2822784u   // [5][2205]
#define OFF_RELC  2833920u   // [75][5][21][441][3]
#define OFF_T2C   13252608u  // [75][5][21][441][3]

__device__ __forceinline__ void top3_insert(float v, float& a, float& b, float& c) {
  bool ga = v > a;
  bool gb = v > b;
  bool gc = v > c;
  float nc = gb ? b : (gc ? v : c);
  float nb = ga ? a : (gb ? v : b);
  float na = ga ? v : a;
  a = na; b = nb; c = nc;
}

__device__ __forceinline__ ushort f2bf(float x) {   // f32 -> bf16 RNE
  uint u = __float_as_uint(x);
  return (ushort)((u + 0x7FFFu + ((u >> 16) & 1u)) >> 16);
}
__device__ __forceinline__ float bf2f(ushort h) { return __uint_as_float(((uint)h) << 16); }

// ---------------- normalize x1 -> qn[q][l][c] ----------------
__global__ __launch_bounds__(256) void norm_q_kernel(const float* __restrict__ x,
                                                     float* __restrict__ outn) {
  const int img  = blockIdx.x;   // 0..74
  const int tile = blockIdx.y;   // 0..6
  __shared__ float tbuf[64][65];
  __shared__ float part[4][64];
  __shared__ float rn[64];
  const int t  = threadIdx.x;
  const int l0 = tile * 64;
  for (int k = 0; k < 16; k++) {
    int idx = t + k * 256;
    int c = idx >> 6, j = idx & 63;
    int l = l0 + j;
    tbuf[c][j] = (l < LL) ? x[(img * CC + c) * LL + l] : 1.0f;
  }
  __syncthreads();
  {
    int j = t & 63, q4 = t >> 6;
    float s = 0.0f;
    for (int c = q4 * 16; c < q4 * 16 + 16; c++) { float v = tbuf[c][j]; s += v * v; }
    part[q4][j] = s;
  }
  __syncthreads();
  if (t < 64) rn[t] = 1.0f / sqrtf(part[0][t] + part[1][t] + part[2][t] + part[3][t]);
  __syncthreads();
  for (int k = 0; k < 16; k++) {
    int idx = t + k * 256;
    int j = idx >> 6, c = idx & 63;
    int l = l0 + j;
    if (l < LL) outn[(img * (size_t)LL + l) * CC + c] = tbuf[c][j] * rn[j];
  }
}

// ---------------- normalize x2 -> supn[w][s][c], s = shot*441 + l2 ----------------
__global__ __launch_bounds__(256) void norm_s_kernel(const float* __restrict__ x,
                                                     float* __restrict__ supn) {
  const int img  = blockIdx.x;   // 0..24
  const int tile = blockIdx.y;   // 0..6
  __shared__ float tbuf[64][65];
  __shared__ float part[4][64];
  __shared__ float rn[64];
  const int t  = threadIdx.x;
  const int l0 = tile * 64;
  const int wv = img / NSHOT, sh = img % NSHOT;
  for (int k = 0; k < 16; k++) {
    int idx = t + k * 256;
    int c = idx >> 6, j = idx & 63;
    int l = l0 + j;
    tbuf[c][j] = (l < LL) ? x[(img * CC + c) * LL + l] : 1.0f;
  }
  __syncthreads();
  {
    int j = t & 63, q4 = t >> 6;
    float s = 0.0f;
    for (int c = q4 * 16; c < q4 * 16 + 16; c++) { float v = tbuf[c][j]; s += v * v; }
    part[q4][j] = s;
  }
  __syncthreads();
  if (t < 64) rn[t] = 1.0f / sqrtf(part[0][t] + part[1][t] + part[2][t] + part[3][t]);
  __syncthreads();
  for (int k = 0; k < 16; k++) {
    int idx = t + k * 256;
    int j = idx >> 6, c = idx & 63;
    int l = l0 + j;
    if (l < LL) supn[((size_t)wv * SS + sh * LL + l) * CC + c] = tbuf[c][j] * rn[j];
  }
}

// ---------------- proto[p][c] = mean_s supn[p][s][c] ----------------
__global__ __launch_bounds__(256) void proto_kernel(const float* __restrict__ supn,
                                                    float* __restrict__ proto) {
  const int p = blockIdx.x;
  const int t = threadIdx.x;
  __shared__ float part[4][64];
  const int c = t & 63, q4 = t >> 6;
  float s = 0.0f;
  for (int sidx = q4; sidx < SS; sidx += 4) s += supn[((size_t)p * SS + sidx) * CC + c];
  part[q4][c] = s;
  __syncthreads();
  if (t < 64)
    proto[p * CC + t] = (part[0][t] + part[1][t] + part[2][t] + part[3][t]) * (1.0f / SS);
}

// ---------------- v[c] = sum_p W_support[p] * proto[p][c] ----------------
__global__ __launch_bounds__(64) void vvec_kernel(const float* __restrict__ proto,
                                                  const float* __restrict__ Wsup,
                                                  float* __restrict__ v) {
  const int c = threadIdx.x;
  float s = 0.0f;
  for (int p = 0; p < NWAY; p++) s += Wsup[p] * proto[p * CC + c];
  v[c] = s;
}

// ---------------- sw[w*SS+s] = sigmoid(v . supn[w][s] + b_support) ----------------
__global__ __launch_bounds__(256) void sw_kernel(const float* __restrict__ supn,
                                                 const float* __restrict__ v,
                                                 const float* __restrict__ bsup,
                                                 float* __restrict__ sw) {
  const int idx = blockIdx.x * 256 + threadIdx.x;
  if (idx >= NWAY * SS) return;
  const float4* row = (const float4*)(supn + (size_t)idx * CC);
  const float4* vv  = (const float4*)v;
  float s = 0.0f;
#pragma unroll
  for (int k = 0; k < 16; k++) {
    float4 a = row[k], b = vv[k];
    s += a.x * b.x + a.y * b.y + a.z * b.z + a.w * b.w;
  }
  sw[idx] = 1.0f / (1.0f + expf(-(s + bsup[0])));
}

// ---------------- main fused kernel (v7: bf16-split MFMA, audited x3) ----------------
// Per block (q, w, strip). Dots on matrix cores via 3-term bf16 hi/lo split
// (error ~2e-5/dot, ll term dropped). Per band of 32 q-rows:
//   MFMA 16 tiles (8 slot-tiles x 2 l-tiles; 2x2 per wave with hoisted
//   fragment loads -> 16 ds_read_b128/wave/band), D -> dotb[slot][l] LDS;
//   group-max(5 slots) -> Ab; t2 top3 (8 thr/row + shfl butterfly);
//   3x3 conv + strip top3 (8 thr/row + butterfly) -> relc.
// LDS fragment tiles XOR-swizzled (byte ^= (row&7)<<4): 2-way max on b128.
// dotb stride 34 -> <=2-way on all access patterns. ~61.3 KB -> 2 blocks/CU.
__global__ __launch_bounds__(256, 2) void main_kernel(
    const float* __restrict__ qn, const float* __restrict__ supn,
    const float* __restrict__ sw, const float* __restrict__ ck,
    const float* __restrict__ cb, float* __restrict__ relc, float* __restrict__ t2c) {
  const int t = threadIdx.x;

  // bijective XCD chunk swizzle (q-major ordering)
  const int bid = blockIdx.x;
  const int xcd = bid & 7, pos = bid >> 3;
  const int qd = NWG / 8;            // 984
  const int rm = NWG - qd * 8;       // 3
  const int base = (xcd < rm) ? xcd * (qd + 1) : rm * (qd + 1) + (xcd - rm) * qd;
  const int oid = base + pos;
  const int q = oid / 105;
  const int rem2 = oid - q * 105;
  const int w = rem2 / 21;
  const int strip = rem2 - w * 21;

  __shared__ __align__(16) ushort sh_l[128 * 64];  // sup hi bf16, swizzled rows
  __shared__ __align__(16) ushort sl_l[128 * 64];  // sup lo
  __shared__ __align__(16) ushort qh_l[32 * 64];   // q hi (current band)
  __shared__ __align__(16) ushort ql_l[32 * 64];   // q lo
  __shared__ float dotb[128 * 34];                 // [slot][l], stride 34
  __shared__ float Ab[34][25];                     // rolling A rows (conv input)
  __shared__ float sws_s[120];
  __shared__ float ckl9[9];
  __shared__ float cbl_s;

  const int s_base = 105 * strip - 5;  // first staged s (group 21*strip - 1)

  // ---- stage sup panel: f32 -> bf16 hi/lo, swizzled [slot][c] ----
  for (int i = t; i < 960; i += TB) {   // 120 slots x 8 chunks of 8 c
    int slot = i >> 3, ch = i & 7;
    int sg = s_base + slot;
    float v[8];
    if (sg >= 0 && sg < SS) {
      const float4* p = (const float4*)&supn[((size_t)w * SS + sg) * CC + ch * 8];
      float4 a = p[0], b = p[1];
      v[0] = a.x; v[1] = a.y; v[2] = a.z; v[3] = a.w;
      v[4] = b.x; v[5] = b.y; v[6] = b.z; v[7] = b.w;
    } else {
#pragma unroll
      for (int j = 0; j < 8; j++) v[j] = 0.0f;
    }
    bf16x8 hi, lo;
#pragma unroll
    for (int j = 0; j < 8; j++) {
      ushort h = f2bf(v[j]);
      hi[j] = (short)h;
      lo[j] = (short)f2bf(v[j] - bf2f(h));
    }
    int byte = slot * 128 + ((ch * 16) ^ ((slot & 7) << 4));
    *(bf16x8*)((char*)sh_l + byte) = hi;
    *(bf16x8*)((char*)sl_l + byte) = lo;
  }
  if (t < 64) {  // zero pad slots 120..127
    int slot = 120 + (t >> 3), ch = t & 7;
    bf16x8 z = {0, 0, 0, 0, 0, 0, 0, 0};
    int byte = slot * 128 + ((ch * 16) ^ ((slot & 7) << 4));
    *(bf16x8*)((char*)sh_l + byte) = z;
    *(bf16x8*)((char*)sl_l + byte) = z;
  }
  for (int i = t; i < 120; i += TB) {
    int sg = s_base + i;
    sws_s[i] = (sg >= 0 && sg < SS) ? sw[w * SS + sg] : 0.0f;
  }
  if (t < 9) ckl9[t] = ck[t];
  if (t == 0) cbl_s = cb[0];
  if (t < 50) Ab[t / 25][t % 25] = 0.0f;
  __syncthreads();

  const int lane = t & 63, wid = t >> 6;
  const int lrow = lane & 15, lhi = lane >> 4;
  const int swz = (lrow & 7) << 4;   // same for all fragment rows (row&7 == lrow&7)

  for (int band = 0; band < 14; band++) {
    const int r0 = band * 32;

    // ---- stage q band: f32 -> bf16 hi/lo (256 tasks = 32 rows x 8 chunks) ----
    {
      int row = t >> 3, ch = t & 7;
      int l = r0 + row;
      float v[8];
      if (l < LL) {
        const float4* p = (const float4*)&qn[((size_t)q * LL + l) * CC + ch * 8];
        float4 a = p[0], b = p[1];
        v[0] = a.x; v[1] = a.y; v[2] = a.z; v[3] = a.w;
        v[4] = b.x; v[5] = b.y; v[6] = b.z; v[7] = b.w;
      } else {
#pragma unroll
        for (int j = 0; j < 8; j++) v[j] = 0.0f;
      }
      bf16x8 hi, lo;
#pragma unroll
      for (int j = 0; j < 8; j++) {
        ushort h = f2bf(v[j]);
        hi[j] = (short)h;
        lo[j] = (short)f2bf(v[j] - bf2f(h));
      }
      int byte = row * 128 + ((ch * 16) ^ ((row & 7) << 4));
      *(bf16x8*)((char*)qh_l + byte) = hi;
      *(bf16x8*)((char*)ql_l + byte) = lo;
    }
    __syncthreads();

    // ---- MFMA: wave wid owns slot-tiles {2wid, 2wid+1} x l-tiles {0,1} ----
    {
      f32x4 acc00 = {0.f, 0.f, 0.f, 0.f};
      f32x4 acc01 = {0.f, 0.f, 0.f, 0.f};
      f32x4 acc10 = {0.f, 0.f, 0.f, 0.f};
      f32x4 acc11 = {0.f, 0.f, 0.f, 0.f};
      const int a0row = (wid * 2 + 0) * 16 + lrow;
      const int a1row = (wid * 2 + 1) * 16 + lrow;
      const int b0row = lrow;
      const int b1row = 16 + lrow;
#pragma unroll
      for (int kc = 0; kc < 2; kc++) {
        const int co = (kc * 64 + lhi * 16) ^ swz;
        bf16x8 bh0 = *(const bf16x8*)((const char*)qh_l + b0row * 128 + co);
        bf16x8 bl0 = *(const bf16x8*)((const char*)ql_l + b0row * 128 + co);
        bf16x8 bh1 = *(const bf16x8*)((const char*)qh_l + b1row * 128 + co);
        bf16x8 bl1 = *(const bf16x8*)((const char*)ql_l + b1row * 128 + co);
        bf16x8 ah0 = *(const bf16x8*)((const char*)sh_l + a0row * 128 + co);
        bf16x8 al0 = *(const bf16x8*)((const char*)sl_l + a0row * 128 + co);
        bf16x8 ah1 = *(const bf16x8*)((const char*)sh_l + a1row * 128 + co);
        bf16x8 al1 = *(const bf16x8*)((const char*)sl_l + a1row * 128 + co);
        acc00 = __builtin_amdgcn_mfma_f32_16x16x32_bf16(ah0, bh0, acc00, 0, 0, 0);
        acc00 = __builtin_amdgcn_mfma_f32_16x16x32_bf16(ah0, bl0, acc00, 0, 0, 0);
        acc00 = __builtin_amdgcn_mfma_f32_16x16x32_bf16(al0, bh0, acc00, 0, 0, 0);
        acc01 = __builtin_amdgcn_mfma_f32_16x16x32_bf16(ah0, bh1, acc01, 0, 0, 0);
        acc01 = __builtin_amdgcn_mfma_f32_16x16x32_bf16(ah0, bl1, acc01, 0, 0, 0);
        acc01 = __builtin_amdgcn_mfma_f32_16x16x32_bf16(al0, bh1, acc01, 0, 0, 0);
        acc10 = __builtin_amdgcn_mfma_f32_16x16x32_bf16(ah1, bh0, acc10, 0, 0, 0);
        acc10 = __builtin_amdgcn_mfma_f32_16x16x32_bf16(ah1, bl0, acc10, 0, 0, 0);
        acc10 = __builtin_amdgcn_mfma_f32_16x16x32_bf16(al1, bh0, acc10, 0, 0, 0);
        acc11 = __builtin_amdgcn_mfma_f32_16x16x32_bf16(ah1, bh1, acc11, 0, 0, 0);
        acc11 = __builtin_amdgcn_mfma_f32_16x16x32_bf16(ah1, bl1, acc11, 0, 0, 0);
        acc11 = __builtin_amdgcn_mfma_f32_16x16x32_bf16(al1, bh1, acc11, 0, 0, 0);
      }
      // D layout [m89]: col = lane&15, row = (lane>>4)*4 + reg
      const int sA = (wid * 2 + 0) * 16 + lhi * 4;
      const int sB = (wid * 2 + 1) * 16 + lhi * 4;
      const int lA = 0 * 16 + lrow;
      const int lB = 1 * 16 + lrow;
      dotb[(sA + 0) * 34 + lA] = acc00[0];
      dotb[(sA + 1) * 34 + lA] = acc00[1];
      dotb[(sA + 2) * 34 + lA] = acc00[2];
      dotb[(sA + 3) * 34 + lA] = acc00[3];
      dotb[(sA + 0) * 34 + lB] = acc01[0];
      dotb[(sA + 1) * 34 + lB] = acc01[1];
      dotb[(sA + 2) * 34 + lB] = acc01[2];
      dotb[(sA + 3) * 34 + lB] = acc01[3];
      dotb[(sB + 0) * 34 + lA] = acc10[0];
      dotb[(sB + 1) * 34 + lA] = acc10[1];
      dotb[(sB + 2) * 34 + lA] = acc10[2];
      dotb[(sB + 3) * 34 + lA] = acc10[3];
      dotb[(sB + 0) * 34 + lB] = acc11[0];
      dotb[(sB + 1) * 34 + lB] = acc11[1];
      dotb[(sB + 2) * 34 + lB] = acc11[2];
      dotb[(sB + 3) * 34 + lB] = acc11[3];
    }
    __syncthreads();

    // ---- group-max (5 consecutive slots) -> Ab rows 2..33 ----
    for (int i = t; i < 768; i += TB) {
      int g = i >> 5, l = i & 31;
      const float* col = &dotb[g * 170 + l];
      float m = col[0];
      m = fmaxf(m, col[34]);
      m = fmaxf(m, col[68]);
      m = fmaxf(m, col[102]);
      m = fmaxf(m, col[136]);
      Ab[l + 2][g] = m;
    }
    // ---- t2: top3 of sw*dot over owned slots [5,110), 8 threads per l-row ----
    {
      int ll = t >> 3, chn = t & 7;
      int sstart = 5 + chn * 13;
      int cnt = (chn == 7) ? 14 : 13;
      float a = -3.0e38f, b = -3.0e38f, c3 = -3.0e38f;
      for (int i = 0; i < cnt; i++) {
        int s = sstart + i;
        float v = sws_s[s] * dotb[s * 34 + ll];
        top3_insert(v, a, b, c3);
      }
#pragma unroll
      for (int off = 1; off < 8; off <<= 1) {
        float pa = __shfl_xor(a, off);
        float pb = __shfl_xor(b, off);
        float pc = __shfl_xor(c3, off);
        top3_insert(pa, a, b, c3);
        top3_insert(pb, a, b, c3);
        top3_insert(pc, a, b, c3);
      }
      int l = r0 + ll;
      if (chn == 0 && l < LL) {
        float* p = &t2c[((((size_t)q * NWAY + w) * NSTRIP + strip) * LL + l) * 3];
        p[0] = a; p[1] = b; p[2] = c3;
      }
    }
    __syncthreads();

    // ---- 3x3 conv (SAME) + per-row strip top3, 8 threads per row ----
    {
      int ro = t >> 3, chn = t & 7;
      int cr = r0 - 1 + ro;
      int c0 = chn * 3;
      float a = -3.0e38f, b = -3.0e38f, c3 = -3.0e38f;
      if (cr >= 0 && cr < LL && c0 < 21) {
        float k0 = ckl9[0], k1 = ckl9[1], k2 = ckl9[2];
        float k3 = ckl9[3], k4 = ckl9[4], k5 = ckl9[5];
        float k6 = ckl9[6], k7 = ckl9[7], k8 = ckl9[8];
        float bias = cbl_s;
        float ra[5], rb[5], rc[5];
#pragma unroll
        for (int j = 0; j < 5; j++) {
          ra[j] = Ab[ro][c0 + j];
          rb[j] = Ab[ro + 1][c0 + j];
          rc[j] = Ab[ro + 2][c0 + j];
        }
#pragma unroll
        for (int i = 0; i < 3; i++) {   // cols c0..c0+2 (21 = 7 chunks x 3; chn 7 idle)
          float s = bias;
          s = fmaf(k0, ra[i], s); s = fmaf(k1, ra[i + 1], s); s = fmaf(k2, ra[i + 2], s);
          s = fmaf(k3, rb[i], s); s = fmaf(k4, rb[i + 1], s); s = fmaf(k5, rb[i + 2], s);
          s = fmaf(k6, rc[i], s); s = fmaf(k7, rc[i + 1], s); s = fmaf(k8, rc[i + 2], s);
          top3_insert(s, a, b, c3);
        }
      }
#pragma unroll
      for (int off = 1; off < 8; off <<= 1) {
        float pa = __shfl_xor(a, off);
        float pb = __shfl_xor(b, off);
        float pc = __shfl_xor(c3, off);
        top3_insert(pa, a, b, c3);
        top3_insert(pb, a, b, c3);
        top3_insert(pc, a, b, c3);
      }
      if (chn == 0 && cr >= 0 && cr < LL) {
        float* p = &relc[((((size_t)q * NWAY + w) * NSTRIP + strip) * LL + cr) * 3];
        p[0] = a; p[1] = b; p[2] = c3;
      }
    }
    __syncthreads();
    // roll last two A rows to front (conv halo carry). Next Ab access
    // (group-max write / conv read) is >=2 barriers away -> no extra barrier.
    if (t < 50) {
      int r2 = t / 25, col = t % 25;
      Ab[r2][col] = Ab[32 + r2][col];
    }
  }
}

// ---------------- final merge: relation, wq, t2, output ----------------
__global__ __launch_bounds__(512) void final_kernel(const float* __restrict__ relc,
                                                    const float* __restrict__ t2c,
                                                    const float* __restrict__ Ww,
                                                    const float* __restrict__ bw,
                                                    float* __restrict__ out) {
  const int q = blockIdx.x;
  const int l = threadIdx.x;
  float contrib[NWAY];
  if (l < LL) {
    float relsum[NWAY], t2sum[NWAY];
    for (int w = 0; w < NWAY; w++) {
      const float* pr = &relc[(((size_t)q * NWAY + w) * NSTRIP) * LL * 3 + (size_t)l * 3];
      float a = -3.0e38f, b = -3.0e38f, c = -3.0e38f;
      for (int stp = 0; stp < NSTRIP; stp++) {
        const float* pp = pr + (size_t)stp * LL * 3;
        top3_insert(pp[0], a, b, c);
        top3_insert(pp[1], a, b, c);
        top3_insert(pp[2], a, b, c);
      }
      relsum[w] = a + b + c;
      const float* pt = &t2c[(((size_t)q * NWAY + w) * NSTRIP) * LL * 3 + (size_t)l * 3];
      a = -3.0e38f; b = -3.0e38f; c = -3.0e38f;
      for (int stp = 0; stp < NSTRIP; stp++) {
        const float* pp = pt + (size_t)stp * LL * 3;
        top3_insert(pp[0], a, b, c);
        top3_insert(pp[1], a, b, c);
        top3_insert(pp[2], a, b, c);
      }
      t2sum[w] = a + b + c;
    }
    float z = bw[0];
    for (int w = 0; w < NWAY; w++) z += Ww[w] * relsum[w];
    float wq = 1.0f / (1.0f + expf(-z));
    for (int w = 0; w < NWAY; w++) contrib[w] = wq * t2sum[w];
  } else {
    for (int w = 0; w < NWAY; w++) contrib[w] = 0.0f;
  }
  __shared__ float red[512];
  for (int w = 0; w < NWAY; w++) {
    red[threadIdx.x] = contrib[w];
    __syncthreads();
    for (int s = 256; s > 0; s >>= 1) {
      if (threadIdx.x < s) red[threadIdx.x] += red[threadIdx.x + s];
      __syncthreads();
    }
    if (threadIdx.x == 0) out[q * NWAY + w] = red[0];
    __syncthreads();
  }
}

extern "C" void kernel_launch(void* const* d_in, const int* in_sizes, int n_in,
                              void* d_out, int out_size, void* d_ws, size_t ws_size,
                              hipStream_t stream) {
  (void)in_sizes; (void)n_in; (void)out_size; (void)ws_size;
  const float* x1   = (const float*)d_in[0];
  const float* x2   = (const float*)d_in[1];
  const float* Wsup = (const float*)d_in[2];
  const float* bsup = (const float*)d_in[3];
  const float* ck   = (const float*)d_in[4];
  const float* cb   = (const float*)d_in[5];
  const float* Ww   = (const float*)d_in[6];
  const float* bw   = (const float*)d_in[7];
  float* out = (float*)d_out;
  float* ws  = (float*)d_ws;

  float* qn    = ws + OFF_QN;
  float* supn  = ws + OFF_SUPN;
  float* proto = ws + OFF_PROTO;
  float* v     = ws + OFF_V;
  float* swp   = ws + OFF_SW;
  float* relc  = ws + OFF_RELC;
  float* t2c   = ws + OFF_T2C;

  hipLaunchKernelGGL(norm_q_kernel, dim3(NQ, 7), dim3(256), 0, stream, x1, qn);
  hipLaunchKernelGGL(norm_s_kernel, dim3(NWAY * NSHOT, 7), dim3(256), 0, stream, x2, supn);
  hipLaunchKernelGGL(proto_kernel, dim3(NWAY), dim3(256), 0, stream, supn, proto);
  hipLaunchKernelGGL(vvec_kernel, dim3(1), dim3(64), 0, stream, proto, Wsup, v);
  hipLaunchKernelGGL(sw_kernel, dim3((NWAY * SS + 255) / 256), dim3(256), 0, stream,
                     supn, v, bsup, swp);
  hipLaunchKernelGGL(main_kernel, dim3(NWG), dim3(TB), 0, stream,
                     qn, supn, swp, ck, cb, relc, t2c);
  hipLaunchKernelGGL(final_kernel, dim3(NQ), dim3(512), 0, stream, relc, t2c, Ww, bw, out);
}